// Round 1
// baseline (1191.792 us; speedup 1.0000x reference)
//
#include <hip/hip_runtime.h>
#include <math.h>

#define BS   16
#define LL   2048
#define DIMC 512
#define NG   2
#define VD   256
#define NC   320
#define NELEM ((double)(VD*LL))   // 524288 per (b,g)

// ---------------------------------------------------------------------------
// Kernel 1: grouped 1x1 conv (projection) + fp64 sum/sumsq stats per (b,g).
// Tile: 32 positions x one group. ze written to d_out in final [b][l][d]
// layout so kernel 3 can operate in-place per-block.
// LDS: xs (input tile) + ys (output staging) 32x256 swizzled = 64 KB.
// Swizzle: logical col c of row r lives at ((c + 4r) & 255) -> conflict-free
// b128 column-of-rows access (lane = row).
// ---------------------------------------------------------------------------
__global__ __launch_bounds__(256, 2) void k_proj(
    const float* __restrict__ x, const float* __restrict__ W,
    float* __restrict__ ze, double* __restrict__ stats)
{
  __shared__ float xs[32 * 256];
  __shared__ float ys[32 * 256];

  const int blk = blockIdx.x;
  const int lt = blk & 63;          // 64 l-tiles of 32
  const int g  = (blk >> 6) & 1;
  const int b  = blk >> 7;
  const int l0 = lt * 32;
  const int t  = threadIdx.x;

  const float* xbase = x + ((size_t)b * LL + l0) * DIMC + g * VD;

  // coalesced load: 32 rows x 256 floats
  #pragma unroll
  for (int it = 0; it < 8; ++it) {
    int q = it * 256 + t;
    int r = q >> 6, c4 = (q & 63) * 4;
    float4 v = *(const float4*)(xbase + (size_t)r * DIMC + c4);
    *(float4*)&xs[r * 256 + ((c4 + 4 * r) & 255)] = v;
  }
  __syncthreads();

  const int lane = t & 63;
  const int w    = t >> 6;
  const int h    = lane >> 5;
  const int p    = lane & 31;
  const float* Wg = W + g * VD * VD;
  double s1 = 0.0, s2 = 0.0;

  for (int j = 0; j < 4; ++j) {
    const int o0 = w * 64 + h * 32 + j * 8;
    float acc[8] = {0.f, 0.f, 0.f, 0.f, 0.f, 0.f, 0.f, 0.f};
    const float* wrow = Wg + o0 * VD;
    for (int v0 = 0; v0 < VD; v0 += 4) {
      float4 a = *(const float4*)&xs[p * 256 + ((v0 + 4 * p) & 255)];
      #pragma unroll
      for (int i = 0; i < 8; ++i) {
        float4 wv = *(const float4*)(wrow + i * VD + v0);
        acc[i] += a.x * wv.x;
        acc[i] += a.y * wv.y;
        acc[i] += a.z * wv.z;
        acc[i] += a.w * wv.w;
      }
    }
    #pragma unroll
    for (int i = 0; i < 8; ++i) { double d = (double)acc[i]; s1 += d; s2 += d * d; }
    *(float4*)&ys[p * 256 + ((o0 + 4 * p) & 255)]     = make_float4(acc[0], acc[1], acc[2], acc[3]);
    *(float4*)&ys[p * 256 + (((o0 + 4) + 4 * p) & 255)] = make_float4(acc[4], acc[5], acc[6], acc[7]);
  }

  // wave-level fp64 reduction, one atomic pair per wave
  #pragma unroll
  for (int off = 32; off > 0; off >>= 1) {
    s1 += __shfl_down(s1, off);
    s2 += __shfl_down(s2, off);
  }
  if (lane == 0) {
    atomicAdd(&stats[(b * NG + g) * 2 + 0], s1);
    atomicAdd(&stats[(b * NG + g) * 2 + 1], s2);
  }

  __syncthreads();
  // coalesced store of ze tile
  float* zbase = ze + ((size_t)b * LL + l0) * DIMC + g * VD;
  #pragma unroll
  for (int it = 0; it < 8; ++it) {
    int q = it * 256 + t;
    int r = q >> 6, c4 = (q & 63) * 4;
    *(float4*)(zbase + (size_t)r * DIMC + c4) = *(const float4*)&ys[r * 256 + ((c4 + 4 * r) & 255)];
  }
}

// ---------------------------------------------------------------------------
// Kernel 2: finalize stats (mean, rstd per (b,g)) + e2[c] = ||emb_c||^2.
// grid = 6 blocks x 64 threads: block 0 -> stats, blocks 1..5 -> 64 codes each.
// ---------------------------------------------------------------------------
__global__ void k_fin(const double* __restrict__ stats,
                      const float* __restrict__ emb,
                      float* __restrict__ msr, float* __restrict__ e2f)
{
  const int t = threadIdx.x;
  if (blockIdx.x == 0) {
    if (t < BS * NG) {
      double s1 = stats[2 * t], s2 = stats[2 * t + 1];
      double mean = s1 / NELEM;
      double var  = s2 / NELEM - mean * mean;
      double rstd = 1.0 / sqrt(var + 1e-5);
      msr[t]      = (float)mean;
      msr[32 + t] = (float)rstd;
    }
  } else {
    const int c = (blockIdx.x - 1) * 64 + t;
    const float* er = emb + (size_t)c * VD;
    double s[4] = {0.0, 0.0, 0.0, 0.0};
    #pragma unroll
    for (int v = 0; v < VD; v += 16) {
      #pragma unroll
      for (int u = 0; u < 4; ++u) {
        float4 e4 = *(const float4*)(er + v + u * 4);
        s[u] += (double)e4.x * e4.x + (double)e4.y * e4.y
              + (double)e4.z * e4.z + (double)e4.w * e4.w;
      }
    }
    e2f[c] = (float)(s[0] + s[1] + s[2] + s[3]);
  }
}

// ---------------------------------------------------------------------------
// Kernel 3: normalize (GroupNorm affine) -> LDS, 320-code distance GEMM with
// streaming argmin (first-min tie semantics), output (zq + z) - z in-place.
// Tile: 32 positions x one group. LDS ~35.5 KB -> 4 blocks/CU.
// ---------------------------------------------------------------------------
__global__ __launch_bounds__(256, 2) void k_vq(
    float* __restrict__ zio, const float* __restrict__ emb,
    const float* __restrict__ gnw, const float* __restrict__ gnb,
    const float* __restrict__ msr, const float* __restrict__ e2f)
{
  __shared__ float zs[32 * 256];
  __shared__ float e2s[NC];
  __shared__ float minv[8][32];
  __shared__ int   mini[8][32];
  __shared__ int   idxs[32];

  const int blk = blockIdx.x;
  const int lt = blk & 63;
  const int g  = (blk >> 6) & 1;
  const int b  = blk >> 7;
  const int l0 = lt * 32;
  const int t  = threadIdx.x;

  const int   sidx = b * NG + g;
  const float mean = msr[sidx];
  const float rstd = msr[32 + sidx];

  for (int c = t; c < NC; c += 256) e2s[c] = e2f[c];

  float* zbase = zio + ((size_t)b * LL + l0) * DIMC + g * VD;
  const float* gw = gnw + g * VD;
  const float* gb = gnb + g * VD;

  // load ze, apply groupnorm, stage swizzled
  #pragma unroll
  for (int it = 0; it < 8; ++it) {
    int q = it * 256 + t;
    int r = q >> 6, c4 = (q & 63) * 4;
    float4 zr = *(const float4*)(zbase + (size_t)r * DIMC + c4);
    float4 w4 = *(const float4*)(gw + c4);
    float4 b4 = *(const float4*)(gb + c4);
    float4 zn;
    { float n = (zr.x - mean) * rstd; zn.x = n * w4.x + b4.x; }
    { float n = (zr.y - mean) * rstd; zn.y = n * w4.y + b4.y; }
    { float n = (zr.z - mean) * rstd; zn.z = n * w4.z + b4.z; }
    { float n = (zr.w - mean) * rstd; zn.w = n * w4.w + b4.w; }
    *(float4*)&zs[r * 256 + ((c4 + 4 * r) & 255)] = zn;
  }
  __syncthreads();

  const int lane = t & 63;
  const int w    = t >> 6;
  const int h    = lane >> 5;
  const int p    = lane & 31;
  const int idx8 = w * 2 + h;          // 8 code-partitions of 40, ascending c

  float best = 3.4e38f; int bi = 0;
  for (int cb = 0; cb < 5; ++cb) {
    const int c0 = idx8 * 40 + cb * 8;
    float acc[8] = {0.f, 0.f, 0.f, 0.f, 0.f, 0.f, 0.f, 0.f};
    const float* er = emb + (size_t)c0 * VD;
    for (int v0 = 0; v0 < VD; v0 += 4) {
      float4 a = *(const float4*)&zs[p * 256 + ((v0 + 4 * p) & 255)];
      #pragma unroll
      for (int i = 0; i < 8; ++i) {
        float4 e4 = *(const float4*)(er + i * VD + v0);
        acc[i] += a.x * e4.x;
        acc[i] += a.y * e4.y;
        acc[i] += a.z * e4.z;
        acc[i] += a.w * e4.w;
      }
    }
    #pragma unroll
    for (int i = 0; i < 8; ++i) {
      float d = e2s[c0 + i] - 2.0f * acc[i];
      if (d < best) { best = d; bi = c0 + i; }   // ascending c -> first-min
    }
  }
  minv[idx8][p] = best; mini[idx8][p] = bi;
  __syncthreads();

  if (t < 32) {
    float bb = minv[0][t]; int ii = mini[0][t];
    #pragma unroll
    for (int k = 1; k < 8; ++k) {
      float v2 = minv[k][t];
      if (v2 < bb) { bb = v2; ii = mini[k][t]; }
    }
    idxs[t] = ii;
  }
  __syncthreads();

  // output: out = (zq + z) - z, exactly replicating the reference STE arith
  #pragma unroll
  for (int it = 0; it < 8; ++it) {
    int q = it * 256 + t;
    int r = q >> 6, c4 = (q & 63) * 4;
    int id = idxs[r];
    float4 zq = *(const float4*)(emb + (size_t)id * VD + c4);
    float4 z4 = *(const float4*)&zs[r * 256 + ((c4 + 4 * r) & 255)];
    float4 o;
    o.x = (zq.x + z4.x) - z4.x;
    o.y = (zq.y + z4.y) - z4.y;
    o.z = (zq.z + z4.z) - z4.z;
    o.w = (zq.w + z4.w) - z4.w;
    *(float4*)(zbase + (size_t)r * DIMC + c4) = o;
  }
}

extern "C" void kernel_launch(void* const* d_in, const int* in_sizes, int n_in,
                              void* d_out, int out_size, void* d_ws, size_t ws_size,
                              hipStream_t stream) {
  const float* x   = (const float*)d_in[0];
  const float* W   = (const float*)d_in[1];   // (2,256,256)
  const float* gnw = (const float*)d_in[2];   // (512,)
  const float* gnb = (const float*)d_in[3];   // (512,)
  const float* emb = (const float*)d_in[4];   // (320,1,256)
  float* out = (float*)d_out;

  double* stats = (double*)d_ws;                        // 64 doubles = 512 B
  float*  msr   = (float*)((char*)d_ws + 512);          // mean[32], rstd[32]
  float*  e2f   = msr + 64;                             // 320 floats

  hipMemsetAsync(d_ws, 0, 512, stream);
  k_proj<<<BS * NG * (LL / 32), 256, 0, stream>>>(x, W, out, stats);
  k_fin<<<6, 64, 0, stream>>>(stats, emb, msr, e2f);
  k_vq<<<BS * NG * (LL / 32), 256, 0, stream>>>(out, emb, gnw, gnb, msr, e2f);
}

// Round 2
// 409.599 us; speedup vs baseline: 2.9097x; 2.9097x over previous
//
#include <hip/hip_runtime.h>
#include <math.h>

#define BS   16
#define LL   2048
#define DIMC 512
#define NG   2
#define VD   256
#define NC   320
#define NELEM ((double)(VD*LL))   // 524288 per (b,g)

// ---------------------------------------------------------------------------
// Kernel 1: grouped 1x1 conv as LDS-staged register-tiled GEMM.
// Per g: C[32768 x 256] = X[32768 x 256] * W_g^T   (out[l][o] = sum_v x*W[o][v])
// Block tile 128 pos x 128 out, 256 threads (16x16), 8x8 register tile.
// K staged in chunks of 32, k-major in LDS so inner-loop reads are b128.
// fp64 sum/sumsq stats per (b,g) via wave reduce + atomics.
// ---------------------------------------------------------------------------
__global__ __launch_bounds__(256, 2) void k_proj(
    const float* __restrict__ x, const float* __restrict__ W,
    float* __restrict__ ze, double* __restrict__ stats)
{
  __shared__ float Xs[32][128];
  __shared__ float Ws[32][128];

  const int blk = blockIdx.x;
  const int nt = blk & 1;           // out-tile (0..1)
  const int g  = (blk >> 1) & 1;
  const int mt = blk >> 2;          // 0..255 position tile
  const int m0 = mt * 128;          // flat position = b*2048 + l
  const int b  = m0 >> 11;
  const int n0 = nt * 128;
  const int t  = threadIdx.x;
  const int tx = t & 15, ty = t >> 4;

  const float* xg = x + (size_t)m0 * DIMC + g * VD;    // row stride DIMC
  const float* Wg = W + ((size_t)g * VD + n0) * VD;    // rows n0.., stride VD

  float acc[8][8];
  #pragma unroll
  for (int i = 0; i < 8; ++i)
    #pragma unroll
    for (int j = 0; j < 8; ++j) acc[i][j] = 0.f;

  for (int k0 = 0; k0 < VD; k0 += 32) {
    // stage X tile: 128 rows x 32 k (coalesced, 8 threads/row), k-major in LDS
    #pragma unroll
    for (int it = 0; it < 4; ++it) {
      int idx = it * 256 + t;
      int row = idx >> 3, q = idx & 7;
      float4 v = *(const float4*)(xg + (size_t)row * DIMC + k0 + q * 4);
      Xs[q * 4 + 0][row] = v.x; Xs[q * 4 + 1][row] = v.y;
      Xs[q * 4 + 2][row] = v.z; Xs[q * 4 + 3][row] = v.w;
    }
    // stage W tile: 128 rows x 32 k
    #pragma unroll
    for (int it = 0; it < 4; ++it) {
      int idx = it * 256 + t;
      int row = idx >> 3, q = idx & 7;
      float4 v = *(const float4*)(Wg + (size_t)row * VD + k0 + q * 4);
      Ws[q * 4 + 0][row] = v.x; Ws[q * 4 + 1][row] = v.y;
      Ws[q * 4 + 2][row] = v.z; Ws[q * 4 + 3][row] = v.w;
    }
    __syncthreads();
    #pragma unroll 8
    for (int kk = 0; kk < 32; ++kk) {
      float4 xa0 = *(const float4*)&Xs[kk][ty * 8];
      float4 xa1 = *(const float4*)&Xs[kk][ty * 8 + 4];
      float4 wb0 = *(const float4*)&Ws[kk][tx * 8];
      float4 wb1 = *(const float4*)&Ws[kk][tx * 8 + 4];
      float xv[8] = {xa0.x, xa0.y, xa0.z, xa0.w, xa1.x, xa1.y, xa1.z, xa1.w};
      float wv[8] = {wb0.x, wb0.y, wb0.z, wb0.w, wb1.x, wb1.y, wb1.z, wb1.w};
      #pragma unroll
      for (int i = 0; i < 8; ++i)
        #pragma unroll
        for (int j = 0; j < 8; ++j) acc[i][j] += xv[i] * wv[j];
    }
    __syncthreads();
  }

  // fp64 stats over this thread's 64 outputs -> wave reduce -> one atomic/wave
  double s1 = 0.0, s2 = 0.0;
  #pragma unroll
  for (int i = 0; i < 8; ++i)
    #pragma unroll
    for (int j = 0; j < 8; ++j) {
      double d = (double)acc[i][j]; s1 += d; s2 += d * d;
    }
  #pragma unroll
  for (int off = 32; off > 0; off >>= 1) {
    s1 += __shfl_down(s1, off);
    s2 += __shfl_down(s2, off);
  }
  if ((t & 63) == 0) {
    atomicAdd(&stats[(b * NG + g) * 2 + 0], s1);
    atomicAdd(&stats[(b * NG + g) * 2 + 1], s2);
  }

  // store C tile
  float* zb = ze + (size_t)m0 * DIMC + g * VD + n0;
  #pragma unroll
  for (int i = 0; i < 8; ++i) {
    float* r = zb + (size_t)(ty * 8 + i) * DIMC + tx * 8;
    *(float4*)(r)     = make_float4(acc[i][0], acc[i][1], acc[i][2], acc[i][3]);
    *(float4*)(r + 4) = make_float4(acc[i][4], acc[i][5], acc[i][6], acc[i][7]);
  }
}

// ---------------------------------------------------------------------------
// Kernel 2: finalize stats (mean, rstd per (b,g)) + e2[c] = ||emb_c||^2.
// ---------------------------------------------------------------------------
__global__ void k_fin(const double* __restrict__ stats,
                      const float* __restrict__ emb,
                      float* __restrict__ msr, float* __restrict__ e2f)
{
  const int t = threadIdx.x;
  if (blockIdx.x == 0) {
    if (t < BS * NG) {
      double s1 = stats[2 * t], s2 = stats[2 * t + 1];
      double mean = s1 / NELEM;
      double var  = s2 / NELEM - mean * mean;
      double rstd = 1.0 / sqrt(var + 1e-5);
      msr[t]      = (float)mean;
      msr[32 + t] = (float)rstd;
    }
  } else {
    const int c = (blockIdx.x - 1) * 64 + t;
    const float* er = emb + (size_t)c * VD;
    double s[4] = {0.0, 0.0, 0.0, 0.0};
    #pragma unroll
    for (int v = 0; v < VD; v += 16) {
      #pragma unroll
      for (int u = 0; u < 4; ++u) {
        float4 e4 = *(const float4*)(er + v + u * 4);
        s[u] += (double)e4.x * e4.x + (double)e4.y * e4.y
              + (double)e4.z * e4.z + (double)e4.w * e4.w;
      }
    }
    e2f[c] = (float)(s[0] + s[1] + s[2] + s[3]);
  }
}

// ---------------------------------------------------------------------------
// Kernel 3: GroupNorm -> VQ distance GEMM (LDS-staged, register-tiled) ->
// argmin (first-min semantics) -> out = (zq + zn) - zn, in-place on zio.
// Block = 64 positions x all 320 codes. Threads: 16 pos-quads x 16 groups-of-20.
// ---------------------------------------------------------------------------
__global__ __launch_bounds__(256, 2) void k_vq(
    float* __restrict__ zio, const float* __restrict__ emb,
    const float* __restrict__ gnw, const float* __restrict__ gnb,
    const float* __restrict__ msr, const float* __restrict__ e2f)
{
  __shared__ float Zs[32][64];
  __shared__ float Es[32][NC];
  __shared__ float e2s[NC];
  __shared__ float bestv[64][16];
  __shared__ int   besti[64][16];
  __shared__ int   idxs[64];

  const int blk = blockIdx.x;
  const int g  = blk & 1;
  const int lt = (blk >> 1) & 31;
  const int b  = blk >> 6;
  const int l0 = lt * 64;
  const int t  = threadIdx.x;
  const int tx = t & 15, ty = t >> 4;   // ty: pos-quad, tx: code-group of 20

  const int   sidx = b * NG + g;
  const float mean = msr[sidx];
  const float rstd = msr[32 + sidx];

  for (int c = t; c < NC; c += 256) e2s[c] = e2f[c];

  float* zbase = zio + ((size_t)(b * LL + l0)) * DIMC + g * VD;
  const float* gw = gnw + g * VD;
  const float* gb = gnb + g * VD;

  float acc[4][20];
  #pragma unroll
  for (int i = 0; i < 4; ++i)
    #pragma unroll
    for (int j = 0; j < 20; ++j) acc[i][j] = 0.f;

  for (int k0 = 0; k0 < VD; k0 += 32) {
    // stage Z (normalized): 64 rows x 32 k
    #pragma unroll
    for (int it = 0; it < 2; ++it) {
      int idx = it * 256 + t;           // 0..511
      int row = idx >> 3, q = idx & 7;
      float4 v  = *(const float4*)(zbase + (size_t)row * DIMC + k0 + q * 4);
      float4 w4 = *(const float4*)(gw + k0 + q * 4);
      float4 b4 = *(const float4*)(gb + k0 + q * 4);
      float n;
      n = (v.x - mean) * rstd; Zs[q * 4 + 0][row] = n * w4.x + b4.x;
      n = (v.y - mean) * rstd; Zs[q * 4 + 1][row] = n * w4.y + b4.y;
      n = (v.z - mean) * rstd; Zs[q * 4 + 2][row] = n * w4.z + b4.z;
      n = (v.w - mean) * rstd; Zs[q * 4 + 3][row] = n * w4.w + b4.w;
    }
    // stage E: 320 rows x 32 k (L2-resident after first touch)
    #pragma unroll
    for (int it = 0; it < 10; ++it) {
      int idx = it * 256 + t;           // 0..2559
      int row = idx >> 3, q = idx & 7;  // row = code 0..319
      float4 v = *(const float4*)(emb + (size_t)row * VD + k0 + q * 4);
      Es[q * 4 + 0][row] = v.x; Es[q * 4 + 1][row] = v.y;
      Es[q * 4 + 2][row] = v.z; Es[q * 4 + 3][row] = v.w;
    }
    __syncthreads();
    #pragma unroll 4
    for (int kk = 0; kk < 32; ++kk) {
      float4 za = *(const float4*)&Zs[kk][ty * 4];
      float zv[4] = {za.x, za.y, za.z, za.w};
      float ev[20];
      #pragma unroll
      for (int u = 0; u < 5; ++u) {
        float4 e4 = *(const float4*)&Es[kk][tx * 20 + u * 4];
        ev[u * 4 + 0] = e4.x; ev[u * 4 + 1] = e4.y;
        ev[u * 4 + 2] = e4.z; ev[u * 4 + 3] = e4.w;
      }
      #pragma unroll
      for (int i = 0; i < 4; ++i)
        #pragma unroll
        for (int j = 0; j < 20; ++j) acc[i][j] += zv[i] * ev[j];
    }
    __syncthreads();
  }

  // per-thread best over its 20 codes (ascending c, strict < -> first-min)
  const int c0 = tx * 20;
  #pragma unroll
  for (int i = 0; i < 4; ++i) {
    float bv = 3.4e38f; int bi = 0;
    #pragma unroll
    for (int j = 0; j < 20; ++j) {
      float d = e2s[c0 + j] - 2.0f * acc[i][j];
      if (d < bv) { bv = d; bi = c0 + j; }
    }
    bestv[ty * 4 + i][tx] = bv; besti[ty * 4 + i][tx] = bi;
  }
  __syncthreads();

  if (t < 64) {
    float bv = bestv[t][0]; int bi = besti[t][0];
    #pragma unroll
    for (int k = 1; k < 16; ++k) {
      float v = bestv[t][k];
      if (v < bv) { bv = v; bi = besti[t][k]; }   // ascending tx -> first-min
    }
    idxs[t] = bi;
  }
  __syncthreads();

  // epilogue: re-read ze, recompute zn identically, out = (zq + zn) - zn
  #pragma unroll
  for (int it = 0; it < 16; ++it) {
    int idx = it * 256 + t;             // 0..4095
    int row = idx >> 6, q4 = (idx & 63) * 4;
    int id = idxs[row];
    float4 zr = *(const float4*)(zbase + (size_t)row * DIMC + q4);
    float4 w4 = *(const float4*)(gw + q4);
    float4 b4 = *(const float4*)(gb + q4);
    float4 e4 = *(const float4*)(emb + (size_t)id * VD + q4);
    float4 o; float n, zn;
    n = (zr.x - mean) * rstd; zn = n * w4.x + b4.x; o.x = (e4.x + zn) - zn;
    n = (zr.y - mean) * rstd; zn = n * w4.y + b4.y; o.y = (e4.y + zn) - zn;
    n = (zr.z - mean) * rstd; zn = n * w4.z + b4.z; o.z = (e4.z + zn) - zn;
    n = (zr.w - mean) * rstd; zn = n * w4.w + b4.w; o.w = (e4.w + zn) - zn;
    *(float4*)(zbase + (size_t)row * DIMC + q4) = o;
  }
}

extern "C" void kernel_launch(void* const* d_in, const int* in_sizes, int n_in,
                              void* d_out, int out_size, void* d_ws, size_t ws_size,
                              hipStream_t stream) {
  const float* x   = (const float*)d_in[0];
  const float* W   = (const float*)d_in[1];   // (2,256,256)
  const float* gnw = (const float*)d_in[2];   // (512,)
  const float* gnb = (const float*)d_in[3];   // (512,)
  const float* emb = (const float*)d_in[4];   // (320,1,256)
  float* out = (float*)d_out;

  double* stats = (double*)d_ws;                        // 64 doubles = 512 B
  float*  msr   = (float*)((char*)d_ws + 512);          // mean[32], rstd[32]
  float*  e2f   = msr + 64;                             // 320 floats

  hipMemsetAsync(d_ws, 0, 512, stream);
  k_proj<<<256 * 2 * NG, 256, 0, stream>>>(x, W, out, stats);
  k_fin<<<6, 64, 0, stream>>>(stats, emb, msr, e2f);
  k_vq<<<BS * NG * (LL / 64), 256, 0, stream>>>(out, emb, gnw, gnb, msr, e2f);
}

// Round 3
// 231.744 us; speedup vs baseline: 5.1427x; 1.7675x over previous
//
#include <hip/hip_runtime.h>
#include <math.h>

typedef _Float16 half8_t  __attribute__((ext_vector_type(8)));
typedef _Float16 half4_t  __attribute__((ext_vector_type(4)));
typedef float    floatx16 __attribute__((ext_vector_type(16)));

#define BS   16
#define LL   2048
#define DIMC 512
#define NG   2
#define VD   256
#define NC   320
#define NELEM ((double)(VD*LL))   // 524288 per (b,g)

// ---------------------------------------------------------------------------
// k_prep: split 16*W and 64*emb into f16 hi/lo pairs (3-term split GEMM).
// Scaling keeps the lo halves in f16 NORMAL range (subnormal flush in MFMA
// would cost ~1e-4 in dist -> argmin flips). Scales are powers of 2 (exact).
// ---------------------------------------------------------------------------
__global__ void k_prep(const float* __restrict__ W, const float* __restrict__ emb,
                       _Float16* __restrict__ Whg, _Float16* __restrict__ Wlg,
                       _Float16* __restrict__ Ehg, _Float16* __restrict__ Elg)
{
  int id = blockIdx.x * 256 + threadIdx.x;
  if (id < NG * VD * VD) {
    float w = W[id] * 16.0f;
    _Float16 h = (_Float16)w;
    Whg[id] = h;
    Wlg[id] = (_Float16)(w - (float)h);
  } else {
    int j = id - NG * VD * VD;
    if (j < NC * VD) {
      float e = emb[j] * 64.0f;
      _Float16 h = (_Float16)e;
      Ehg[j] = h;
      Elg[j] = (_Float16)(e - (float)h);
    }
  }
}

// ---------------------------------------------------------------------------
// k_proj: ze = X * (16W)^T / 16 via mfma_f32_32x32x16_f16, 3-term split.
// Block tile 128x128, 4 waves (2x2 of 64x64), wave = 2x2 MFMA tiles of 32x32.
// K chunked at 32: LDS row = [hi(32) | lo(32) | pad 8] stride 72 f16 = 144 B
// (16B-aligned rows, 4-words-mod-32 bank stagger -> b128 frag reads at floor).
// fp64 sum/sumsq stats per (b,g) for GroupNorm.
// ---------------------------------------------------------------------------
__global__ __launch_bounds__(256, 2) void k_proj(
    const float* __restrict__ x,
    const _Float16* __restrict__ Whg, const _Float16* __restrict__ Wlg,
    float* __restrict__ ze, double* __restrict__ stats)
{
  __shared__ _Float16 Ah[128][72];
  __shared__ _Float16 Bh[128][72];

  const int blk = blockIdx.x;
  const int g  = blk & 1;
  const int nb = (blk >> 1) & 1;
  const int mt = blk >> 2;
  const int m0 = mt * 128;          // flat position b*2048+l
  const int n0 = nb * 128;
  const int b  = m0 >> 11;
  const int t  = threadIdx.x;
  const int lane = t & 63;
  const int w    = t >> 6;
  const int col  = lane & 31;
  const int hq   = lane >> 5;
  const int mw   = (w & 1) * 64;
  const int nw   = (w >> 1) * 64;

  floatx16 acc[2][2];
  #pragma unroll
  for (int i = 0; i < 2; ++i)
    #pragma unroll
    for (int j = 0; j < 2; ++j)
      #pragma unroll
      for (int e = 0; e < 16; ++e) acc[i][j][e] = 0.f;

  for (int k0 = 0; k0 < VD; k0 += 32) {
    // stage X chunk: 128 rows x 32 k, split on the fly
    #pragma unroll
    for (int i = 0; i < 4; ++i) {
      int idx = i * 256 + t;
      int row = idx >> 3, kq = idx & 7;
      float4 v = *(const float4*)(x + ((size_t)(m0 + row)) * DIMC + g * VD + k0 + kq * 4);
      half4_t hh, ll;
      { _Float16 h = (_Float16)v.x; hh[0] = h; ll[0] = (_Float16)(v.x - (float)h); }
      { _Float16 h = (_Float16)v.y; hh[1] = h; ll[1] = (_Float16)(v.y - (float)h); }
      { _Float16 h = (_Float16)v.z; hh[2] = h; ll[2] = (_Float16)(v.z - (float)h); }
      { _Float16 h = (_Float16)v.w; hh[3] = h; ll[3] = (_Float16)(v.w - (float)h); }
      *(half4_t*)&Ah[row][kq * 4]      = hh;
      *(half4_t*)&Ah[row][32 + kq * 4] = ll;
    }
    // stage W chunk (pre-split f16): 128 rows x 32 k, hi+lo
    #pragma unroll
    for (int i = 0; i < 2; ++i) {
      int idx = i * 256 + t;
      int row = idx >> 2, kc = idx & 3;
      size_t off = ((size_t)(g * VD + n0 + row)) * VD + k0 + kc * 8;
      *(half8_t*)&Bh[row][kc * 8]      = *(const half8_t*)(Whg + off);
      *(half8_t*)&Bh[row][32 + kc * 8] = *(const half8_t*)(Wlg + off);
    }
    __syncthreads();
    #pragma unroll
    for (int ks = 0; ks < 2; ++ks) {
      const int ko = ks * 16 + hq * 8;
      half8_t azh[2], azl[2], bwh[2], bwl[2];
      #pragma unroll
      for (int i2 = 0; i2 < 2; ++i2) {
        azh[i2] = *(const half8_t*)&Ah[mw + i2 * 32 + col][ko];
        azl[i2] = *(const half8_t*)&Ah[mw + i2 * 32 + col][32 + ko];
        bwh[i2] = *(const half8_t*)&Bh[nw + i2 * 32 + col][ko];
        bwl[i2] = *(const half8_t*)&Bh[nw + i2 * 32 + col][32 + ko];
      }
      #pragma unroll
      for (int mi = 0; mi < 2; ++mi)
        #pragma unroll
        for (int ni = 0; ni < 2; ++ni) {
          acc[mi][ni] = __builtin_amdgcn_mfma_f32_32x32x16_f16(azh[mi], bwh[ni], acc[mi][ni], 0, 0, 0);
          acc[mi][ni] = __builtin_amdgcn_mfma_f32_32x32x16_f16(azh[mi], bwl[ni], acc[mi][ni], 0, 0, 0);
          acc[mi][ni] = __builtin_amdgcn_mfma_f32_32x32x16_f16(azl[mi], bwh[ni], acc[mi][ni], 0, 0, 0);
        }
    }
    __syncthreads();
  }

  // epilogue: scale back by 1/16 (exact), store, fp64 stats
  double s1 = 0.0, s2 = 0.0;
  #pragma unroll
  for (int mi = 0; mi < 2; ++mi)
    #pragma unroll
    for (int ni = 0; ni < 2; ++ni)
      #pragma unroll
      for (int r = 0; r < 16; ++r) {
        float vv = acc[mi][ni][r] * 0.0625f;
        double d = (double)vv; s1 += d; s2 += d * d;
        int ml = mw + mi * 32 + (r & 3) + 8 * (r >> 2) + 4 * hq;
        int nl = nw + ni * 32 + col;
        ze[((size_t)(m0 + ml)) * DIMC + g * VD + n0 + nl] = vv;
      }
  #pragma unroll
  for (int off = 32; off > 0; off >>= 1) {
    s1 += __shfl_down(s1, off);
    s2 += __shfl_down(s2, off);
  }
  if (lane == 0) {
    atomicAdd(&stats[(b * NG + g) * 2 + 0], s1);
    atomicAdd(&stats[(b * NG + g) * 2 + 1], s2);
  }
}

// ---------------------------------------------------------------------------
// k_fin: mean/rstd per (b,g); e2f[c] = 64 * ||emb_c||^2 (fp64, matches the
// 64x scaling of E so dist' = e2f - 2*dot' = 64*dist -> same argmin).
// ---------------------------------------------------------------------------
__global__ void k_fin(const double* __restrict__ stats,
                      const float* __restrict__ emb,
                      float* __restrict__ msr, float* __restrict__ e2f)
{
  const int t = threadIdx.x;
  if (blockIdx.x == 0) {
    if (t < BS * NG) {
      double s1 = stats[2 * t], s2 = stats[2 * t + 1];
      double mean = s1 / NELEM;
      double var  = s2 / NELEM - mean * mean;
      double rstd = 1.0 / sqrt(var + 1e-5);
      msr[t]      = (float)mean;
      msr[32 + t] = (float)rstd;
    }
  } else {
    const int c = (blockIdx.x - 1) * 64 + t;
    const float* er = emb + (size_t)c * VD;
    double s[4] = {0.0, 0.0, 0.0, 0.0};
    #pragma unroll
    for (int v = 0; v < VD; v += 16) {
      #pragma unroll
      for (int u = 0; u < 4; ++u) {
        float4 e4 = *(const float4*)(er + v + u * 4);
        s[u] += (double)e4.x * e4.x + (double)e4.y * e4.y
              + (double)e4.z * e4.z + (double)e4.w * e4.w;
      }
    }
    e2f[c] = (float)(64.0 * (s[0] + s[1] + s[2] + s[3]));
  }
}

// ---------------------------------------------------------------------------
// k_vq: GroupNorm -> split -> MFMA dots vs all 320 codes -> argmin (first-min
// ascending-c semantics via strict < then lexicographic) -> (zq+zn)-zn.
// Block: 64 positions x 320 codes. Wave w: m-half (w&1), n-half (w>>1) of 160
// (5 MFMA n-tiles). Reduce arrays overlay Es after the k-loop.
// ---------------------------------------------------------------------------
__global__ __launch_bounds__(256, 2) void k_vq(
    float* __restrict__ zio, const float* __restrict__ emb,
    const _Float16* __restrict__ Ehg, const _Float16* __restrict__ Elg,
    const float* __restrict__ gnw, const float* __restrict__ gnb,
    const float* __restrict__ msr, const float* __restrict__ e2f)
{
  __shared__ _Float16 Ah[64][72];
  __shared__ _Float16 Es[320][72];      // 46080 B; overlaid by bestv/besti later
  __shared__ float e2sh[NC];
  __shared__ int idxs[64];

  const int blk = blockIdx.x;
  const int g  = blk & 1;
  const int m0 = (blk >> 1) * 64;       // flat position b*2048+l
  const int b  = m0 >> 11;
  const int t  = threadIdx.x;
  const int lane = t & 63;
  const int w    = t >> 6;
  const int col  = lane & 31;
  const int hq   = lane >> 5;
  const int mhalf = w & 1;
  const int nhalf = w >> 1;
  const int ml = mhalf * 32 + col;

  const float mean = msr[b * NG + g];
  const float rstd = msr[32 + b * NG + g];
  for (int c = t; c < NC; c += 256) e2sh[c] = e2f[c];

  float* zbase = zio + ((size_t)m0) * DIMC + g * VD;
  const float* gw = gnw + g * VD;
  const float* gb = gnb + g * VD;

  floatx16 acc[5];
  #pragma unroll
  for (int i = 0; i < 5; ++i)
    #pragma unroll
    for (int e = 0; e < 16; ++e) acc[i][e] = 0.f;

  for (int k0 = 0; k0 < VD; k0 += 32) {
    // stage Z chunk: GroupNorm in fp32, split to f16 hi/lo
    #pragma unroll
    for (int i = 0; i < 2; ++i) {
      int idx = i * 256 + t;
      int row = idx >> 3, kq = idx & 7;
      float4 v  = *(const float4*)(zbase + ((size_t)row) * DIMC + k0 + kq * 4);
      float4 w4 = *(const float4*)(gw + k0 + kq * 4);
      float4 b4 = *(const float4*)(gb + k0 + kq * 4);
      float zn0 = (v.x - mean) * rstd * w4.x + b4.x;
      float zn1 = (v.y - mean) * rstd * w4.y + b4.y;
      float zn2 = (v.z - mean) * rstd * w4.z + b4.z;
      float zn3 = (v.w - mean) * rstd * w4.w + b4.w;
      half4_t hh, ll;
      { _Float16 h = (_Float16)zn0; hh[0] = h; ll[0] = (_Float16)(zn0 - (float)h); }
      { _Float16 h = (_Float16)zn1; hh[1] = h; ll[1] = (_Float16)(zn1 - (float)h); }
      { _Float16 h = (_Float16)zn2; hh[2] = h; ll[2] = (_Float16)(zn2 - (float)h); }
      { _Float16 h = (_Float16)zn3; hh[3] = h; ll[3] = (_Float16)(zn3 - (float)h); }
      *(half4_t*)&Ah[row][kq * 4]      = hh;
      *(half4_t*)&Ah[row][32 + kq * 4] = ll;
    }
    // stage E chunk (pre-split f16): 320 rows x 32 k, hi+lo
    #pragma unroll
    for (int i = 0; i < 5; ++i) {
      int idx = i * 256 + t;
      int row = idx >> 2, kc = idx & 3;
      size_t off = ((size_t)row) * VD + k0 + kc * 8;
      *(half8_t*)&Es[row][kc * 8]      = *(const half8_t*)(Ehg + off);
      *(half8_t*)&Es[row][32 + kc * 8] = *(const half8_t*)(Elg + off);
    }
    __syncthreads();
    #pragma unroll
    for (int ks = 0; ks < 2; ++ks) {
      const int ko = ks * 16 + hq * 8;
      half8_t azh = *(const half8_t*)&Ah[ml][ko];
      half8_t azl = *(const half8_t*)&Ah[ml][32 + ko];
      #pragma unroll
      for (int nt = 0; nt < 5; ++nt) {
        int nr = nhalf * 160 + nt * 32 + col;
        half8_t beh = *(const half8_t*)&Es[nr][ko];
        half8_t bel = *(const half8_t*)&Es[nr][32 + ko];
        acc[nt] = __builtin_amdgcn_mfma_f32_32x32x16_f16(azh, beh, acc[nt], 0, 0, 0);
        acc[nt] = __builtin_amdgcn_mfma_f32_32x32x16_f16(azh, bel, acc[nt], 0, 0, 0);
        acc[nt] = __builtin_amdgcn_mfma_f32_32x32x16_f16(azl, beh, acc[nt], 0, 0, 0);
      }
    }
    __syncthreads();
  }

  // argmin: per-lane over 5 tiles (ascending n, strict < = first-min), then
  // per-m lexicographic (v, n) scan. Reduce arrays overlay Es (safe post-sync).
  float* bestv = (float*)&Es[0][0];
  int*   besti = (int*)((char*)&Es[0][0] + 64 * 65 * 4);
  #pragma unroll
  for (int r = 0; r < 16; ++r) {
    int mloc = mhalf * 32 + (r & 3) + 8 * (r >> 2) + 4 * hq;
    float bv = 3.4e38f; int bn = 0;
    #pragma unroll
    for (int nt = 0; nt < 5; ++nt) {
      int n = nhalf * 160 + nt * 32 + col;
      float d = e2sh[n] - 2.0f * acc[nt][r];
      if (d < bv) { bv = d; bn = n; }
    }
    bestv[mloc * 65 + nhalf * 32 + col] = bv;
    besti[mloc * 65 + nhalf * 32 + col] = bn;
  }
  __syncthreads();
  if (t < 64) {
    float bv = bestv[t * 65]; int bn = besti[t * 65];
    for (int j = 1; j < 64; ++j) {
      float v = bestv[t * 65 + j]; int n = besti[t * 65 + j];
      if (v < bv || (v == bv && n < bn)) { bv = v; bn = n; }
    }
    idxs[t] = bn;
  }
  __syncthreads();

  // epilogue: re-read ze, recompute zn identically, out = (zq + zn) - zn
  #pragma unroll
  for (int it = 0; it < 16; ++it) {
    int idx = it * 256 + t;             // 0..4095
    int row = idx >> 6, q4 = (idx & 63) * 4;
    int id = idxs[row];
    float4 zr = *(const float4*)(zbase + (size_t)row * DIMC + q4);
    float4 w4 = *(const float4*)(gw + q4);
    float4 b4 = *(const float4*)(gb + q4);
    float4 e4 = *(const float4*)(emb + (size_t)id * VD + q4);
    float4 o; float zn;
    zn = (zr.x - mean) * rstd * w4.x + b4.x; o.x = (e4.x + zn) - zn;
    zn = (zr.y - mean) * rstd * w4.y + b4.y; o.y = (e4.y + zn) - zn;
    zn = (zr.z - mean) * rstd * w4.z + b4.z; o.z = (e4.z + zn) - zn;
    zn = (zr.w - mean) * rstd * w4.w + b4.w; o.w = (e4.w + zn) - zn;
    *(float4*)(zbase + (size_t)row * DIMC + q4) = o;
  }
}

extern "C" void kernel_launch(void* const* d_in, const int* in_sizes, int n_in,
                              void* d_out, int out_size, void* d_ws, size_t ws_size,
                              hipStream_t stream) {
  const float* x   = (const float*)d_in[0];
  const float* W   = (const float*)d_in[1];   // (2,256,256)
  const float* gnw = (const float*)d_in[2];   // (512,)
  const float* gnb = (const float*)d_in[3];   // (512,)
  const float* emb = (const float*)d_in[4];   // (320,1,256)
  float* out = (float*)d_out;

  double*   stats = (double*)d_ws;                          // 512 B
  float*    msr   = (float*)((char*)d_ws + 512);            // 256 B
  float*    e2f   = (float*)((char*)d_ws + 768);            // 1280 B
  _Float16* Whg   = (_Float16*)((char*)d_ws + 4096);        // 262144 B
  _Float16* Wlg   = (_Float16*)((char*)d_ws + 266240);      // 262144 B
  _Float16* Ehg   = (_Float16*)((char*)d_ws + 528384);      // 163840 B
  _Float16* Elg   = (_Float16*)((char*)d_ws + 692224);      // 163840 B -> 856064 total

  hipMemsetAsync(d_ws, 0, 512, stream);
  k_prep<<<(NG * VD * VD + NC * VD + 255) / 256, 256, 0, stream>>>(W, emb, Whg, Wlg, Ehg, Elg);
  k_proj<<<1024, 256, 0, stream>>>(x, Whg, Wlg, out, stats);
  k_fin<<<6, 64, 0, stream>>>(stats, emb, msr, e2f);
  k_vq<<<1024, 256, 0, stream>>>(out, emb, Ehg, Elg, gnw, gnb, msr, e2f);
}

// Round 4
// 208.126 us; speedup vs baseline: 5.7263x; 1.1135x over previous
//
#include <hip/hip_runtime.h>
#include <math.h>

typedef _Float16 half8_t  __attribute__((ext_vector_type(8)));
typedef _Float16 half4_t  __attribute__((ext_vector_type(4)));
typedef float    floatx16 __attribute__((ext_vector_type(16)));

#define BS   16
#define LL   2048
#define DIMC 512
#define NG   2
#define VD   256
#define NC   320
#define NELEM ((double)(VD*LL))   // 524288 per (b,g)

// global -> LDS direct DMA, 16 B per lane. gsrc per-lane, ldst wave-uniform.
#define GLL(gsrc, ldst) __builtin_amdgcn_global_load_lds( \
    (const __attribute__((address_space(1))) unsigned int*)(gsrc), \
    (__attribute__((address_space(3))) unsigned int*)(ldst), 16, 0, 0)

// ---------------------------------------------------------------------------
// k_prep: build chunk-image f16 hi/lo splits for W (x16) and E (x64) in the
// exact LDS layout the GEMM kernels stage with global_load_lds:
//   Wimg[g][chunk 8][row 256][72]  row = outdim, [0..31]=hi [32..63]=lo [64..71]=pad
//   Eimg[chunk 8][code 320][72]
// Also e2f[c] = 64*||E_c||^2 (fp64) and zero stats.
// Power-of-2 scales keep lo-halves in f16 normal range (exact on rescale).
// ---------------------------------------------------------------------------
__global__ void k_prep(const float* __restrict__ W, const float* __restrict__ emb,
                       _Float16* __restrict__ Wimg, _Float16* __restrict__ Eimg,
                       float* __restrict__ e2f, double* __restrict__ stats)
{
  const int blk = blockIdx.x, t = threadIdx.x;
  if (blk < 512) {
    int id = blk * 256 + t;            // flat (g,o,v)
    int k = id & 255, c = k >> 5, kk = k & 31;
    int row = (id >> 8) & 255, g = id >> 16;
    float w = W[id] * 16.0f;
    _Float16 h = (_Float16)w;
    size_t base = ((size_t)(g * 8 + c) * 256 + row) * 72;
    Wimg[base + kk]      = h;
    Wimg[base + 32 + kk] = (_Float16)(w - (float)h);
  } else if (blk < 832) {
    int j = (blk - 512) * 256 + t;     // flat (code,v)
    int k = j & 255, c = k >> 5, kk = k & 31;
    int code = j >> 8;
    float e = emb[j] * 64.0f;
    _Float16 h = (_Float16)e;
    size_t base = ((size_t)c * 320 + code) * 72;
    Eimg[base + kk]      = h;
    Eimg[base + 32 + kk] = (_Float16)(e - (float)h);
  } else if (blk < 834) {
    int code = (blk - 832) * 256 + t;
    if (code < NC) {
      const float* er = emb + (size_t)code * VD;
      double s[4] = {0.0, 0.0, 0.0, 0.0};
      for (int v = 0; v < VD; v += 16)
        #pragma unroll
        for (int u = 0; u < 4; ++u) {
          float4 e4 = *(const float4*)(er + v + u * 4);
          s[u] += (double)e4.x * e4.x + (double)e4.y * e4.y
                + (double)e4.z * e4.z + (double)e4.w * e4.w;
        }
      e2f[code] = (float)(64.0 * (s[0] + s[1] + s[2] + s[3]));
    }
  } else {
    if (t < 64) stats[t] = 0.0;
  }
}

// ---------------------------------------------------------------------------
// k_proj: ze = X * (16W)^T / 16, 3-term f16-split MFMA. Tile 128 pos x 256
// outdim (full group). 4 waves: (w&1) m-half of 64, (w>>1) n-half of 128.
// W chunk staged via global_load_lds from Wimg; X staged manually (split on
// the fly). LDS 55.3 KB -> 2 blocks/CU. fp64 stats per (b,g).
// ---------------------------------------------------------------------------
__global__ __launch_bounds__(256, 2) void k_proj(
    const float* __restrict__ x, const _Float16* __restrict__ Wimg,
    float* __restrict__ ze, double* __restrict__ stats)
{
  __shared__ _Float16 Ah[128][72];
  __shared__ _Float16 Bh[256 * 72];

  const int blk = blockIdx.x;
  const int g  = blk & 1;
  const int m0 = (blk >> 1) * 128;     // flat position b*2048+l
  const int b  = m0 >> 11;
  const int t  = threadIdx.x;
  const int lane = t & 63, w = t >> 6;
  const int col  = lane & 31, hq = lane >> 5;
  const int mw = (w & 1) * 64, nw = (w >> 1) * 128;

  const char* wbase = (const char*)(Wimg + (size_t)g * 8 * 256 * 72);

  floatx16 acc[2][4];
  #pragma unroll
  for (int i = 0; i < 2; ++i)
    #pragma unroll
    for (int j = 0; j < 4; ++j)
      #pragma unroll
      for (int e = 0; e < 16; ++e) acc[i][j][e] = 0.f;

  for (int c = 0; c < 8; ++c) {
    // X chunk: 128 rows x 32 k, split to hi/lo
    #pragma unroll
    for (int i = 0; i < 4; ++i) {
      int idx = i * 256 + t;
      int row = idx >> 3, kq = idx & 7;
      float4 v = *(const float4*)(x + ((size_t)(m0 + row)) * DIMC + g * VD + c * 32 + kq * 4);
      half4_t hh, ll;
      { _Float16 h = (_Float16)v.x; hh[0] = h; ll[0] = (_Float16)(v.x - (float)h); }
      { _Float16 h = (_Float16)v.y; hh[1] = h; ll[1] = (_Float16)(v.y - (float)h); }
      { _Float16 h = (_Float16)v.z; hh[2] = h; ll[2] = (_Float16)(v.z - (float)h); }
      { _Float16 h = (_Float16)v.w; hh[3] = h; ll[3] = (_Float16)(v.w - (float)h); }
      *(half4_t*)&Ah[row][kq * 4]      = hh;
      *(half4_t*)&Ah[row][32 + kq * 4] = ll;
    }
    // W chunk image: 36864 B via global_load_lds (9 wave-loads x 4 waves)
    {
      const char* wc = wbase + (size_t)c * 256 * 144;
      #pragma unroll
      for (int i = 0; i < 9; ++i) {
        int off = (w * 9 + i) * 1024 + lane * 16;
        GLL(wc + off, (char*)Bh + off);
      }
    }
    __syncthreads();
    #pragma unroll
    for (int ks = 0; ks < 2; ++ks) {
      const int ko = ks * 16 + hq * 8;
      half8_t azh[2], azl[2], bwh[4], bwl[4];
      #pragma unroll
      for (int i = 0; i < 2; ++i) {
        azh[i] = *(const half8_t*)&Ah[mw + i * 32 + col][ko];
        azl[i] = *(const half8_t*)&Ah[mw + i * 32 + col][32 + ko];
      }
      #pragma unroll
      for (int j = 0; j < 4; ++j) {
        bwh[j] = *(const half8_t*)&Bh[(nw + j * 32 + col) * 72 + ko];
        bwl[j] = *(const half8_t*)&Bh[(nw + j * 32 + col) * 72 + 32 + ko];
      }
      #pragma unroll
      for (int mi = 0; mi < 2; ++mi)
        #pragma unroll
        for (int ni = 0; ni < 4; ++ni) {
          acc[mi][ni] = __builtin_amdgcn_mfma_f32_32x32x16_f16(azh[mi], bwh[ni], acc[mi][ni], 0, 0, 0);
          acc[mi][ni] = __builtin_amdgcn_mfma_f32_32x32x16_f16(azh[mi], bwl[ni], acc[mi][ni], 0, 0, 0);
          acc[mi][ni] = __builtin_amdgcn_mfma_f32_32x32x16_f16(azl[mi], bwh[ni], acc[mi][ni], 0, 0, 0);
        }
    }
    __syncthreads();
  }

  // epilogue: scale back 1/16 (exact), fp64 stats, coalesced-enough stores
  double s1 = 0.0, s2 = 0.0;
  #pragma unroll
  for (int mi = 0; mi < 2; ++mi)
    #pragma unroll
    for (int ni = 0; ni < 4; ++ni)
      #pragma unroll
      for (int r = 0; r < 16; ++r) {
        float vv = acc[mi][ni][r] * 0.0625f;
        double d = (double)vv; s1 += d; s2 += d * d;
        int ml = mw + mi * 32 + (r & 3) + 8 * (r >> 2) + 4 * hq;
        int nl = nw + ni * 32 + col;
        ze[((size_t)(m0 + ml)) * DIMC + g * VD + nl] = vv;
      }
  #pragma unroll
  for (int off = 32; off > 0; off >>= 1) {
    s1 += __shfl_down(s1, off);
    s2 += __shfl_down(s2, off);
  }
  if (lane == 0) {
    atomicAdd(&stats[(b * NG + g) * 2 + 0], s1);
    atomicAdd(&stats[(b * NG + g) * 2 + 1], s2);
  }
}

// ---------------------------------------------------------------------------
// k_vq: GroupNorm -> split -> flipped MFMA (A = E' codes, B = Z positions):
// D[code][pos], col=lane = pos -> fully in-lane argmin over 160 codes + one
// shfl_xor(32). Tile 128 pos x 320 codes; wave w owns pos-tile w*32.
// E' chunk staged via global_load_lds; mean/rstd finalized inline per thread.
// Epilogue: recompute zn from ze, out = (zq+zn)-zn, in-place.
// ---------------------------------------------------------------------------
__global__ __launch_bounds__(256, 2) void k_vq(
    float* __restrict__ zio, const float* __restrict__ emb,
    const _Float16* __restrict__ Eimg,
    const float* __restrict__ gnw, const float* __restrict__ gnb,
    const double* __restrict__ stats, const float* __restrict__ e2f)
{
  __shared__ _Float16 Zs[128][72];
  __shared__ _Float16 Es[320 * 72];
  __shared__ float e2sh[NC];
  __shared__ int idxs[128];

  const int blk = blockIdx.x;
  const int g  = blk & 1;
  const int m0 = (blk >> 1) * 128;
  const int b  = m0 >> 11;
  const int t  = threadIdx.x;
  const int lane = t & 63, w = t >> 6;
  const int col  = lane & 31, hq = lane >> 5;

  // finalize stats inline (uniform per block; identical fp64 math every call)
  const int si = b * NG + g;
  double ss1 = stats[2 * si], ss2 = stats[2 * si + 1];
  double mu = ss1 / NELEM, var = ss2 / NELEM - mu * mu;
  const float mean = (float)mu;
  const float rstd = (float)(1.0 / sqrt(var + 1e-5));

  for (int c = t; c < NC; c += 256) e2sh[c] = e2f[c];

  float* zbase = zio + (size_t)m0 * DIMC + g * VD;
  const float* gw = gnw + g * VD;
  const float* gb = gnb + g * VD;

  floatx16 acc[10];
  #pragma unroll
  for (int i = 0; i < 10; ++i)
    #pragma unroll
    for (int e = 0; e < 16; ++e) acc[i][e] = 0.f;

  for (int c = 0; c < 8; ++c) {
    // Z chunk: 128 rows x 32 k, GroupNorm + split
    #pragma unroll
    for (int i = 0; i < 4; ++i) {
      int idx = i * 256 + t;
      int row = idx >> 3, kq = idx & 7;
      float4 v  = *(const float4*)(zbase + (size_t)row * DIMC + c * 32 + kq * 4);
      float4 w4 = *(const float4*)(gw + c * 32 + kq * 4);
      float4 b4 = *(const float4*)(gb + c * 32 + kq * 4);
      float zn0 = (v.x - mean) * rstd * w4.x + b4.x;
      float zn1 = (v.y - mean) * rstd * w4.y + b4.y;
      float zn2 = (v.z - mean) * rstd * w4.z + b4.z;
      float zn3 = (v.w - mean) * rstd * w4.w + b4.w;
      half4_t hh, ll;
      { _Float16 h = (_Float16)zn0; hh[0] = h; ll[0] = (_Float16)(zn0 - (float)h); }
      { _Float16 h = (_Float16)zn1; hh[1] = h; ll[1] = (_Float16)(zn1 - (float)h); }
      { _Float16 h = (_Float16)zn2; hh[2] = h; ll[2] = (_Float16)(zn2 - (float)h); }
      { _Float16 h = (_Float16)zn3; hh[3] = h; ll[3] = (_Float16)(zn3 - (float)h); }
      *(half4_t*)&Zs[row][kq * 4]      = hh;
      *(half4_t*)&Zs[row][32 + kq * 4] = ll;
    }
    // E' chunk image: 46080 B via global_load_lds (45 wave-loads over 4 waves)
    {
      const char* ec = (const char*)Eimg + (size_t)c * 320 * 144;
      for (int i = w; i < 45; i += 4) {
        int off = i * 1024 + lane * 16;
        GLL(ec + off, (char*)Es + off);
      }
    }
    __syncthreads();
    #pragma unroll
    for (int ks = 0; ks < 2; ++ks) {
      const int ko = ks * 16 + hq * 8;
      half8_t bzh = *(const half8_t*)&Zs[w * 32 + col][ko];
      half8_t bzl = *(const half8_t*)&Zs[w * 32 + col][32 + ko];
      #pragma unroll
      for (int mt = 0; mt < 10; ++mt) {
        half8_t aeh = *(const half8_t*)&Es[(mt * 32 + col) * 72 + ko];
        half8_t ael = *(const half8_t*)&Es[(mt * 32 + col) * 72 + 32 + ko];
        acc[mt] = __builtin_amdgcn_mfma_f32_32x32x16_f16(aeh, bzh, acc[mt], 0, 0, 0);
        acc[mt] = __builtin_amdgcn_mfma_f32_32x32x16_f16(aeh, bzl, acc[mt], 0, 0, 0);
        acc[mt] = __builtin_amdgcn_mfma_f32_32x32x16_f16(ael, bzh, acc[mt], 0, 0, 0);
      }
    }
    __syncthreads();
  }

  // in-lane argmin over 160 codes (lexicographic (d, code) = first-min), then
  // combine the hq pair with shfl_xor(32). Lane col of wave w owns pos w*32+col.
  float bv = 3.4e38f; int bi = 0x7fffffff;
  #pragma unroll
  for (int mt = 0; mt < 10; ++mt)
    #pragma unroll
    for (int r = 0; r < 16; ++r) {
      int code = mt * 32 + (r & 3) + 8 * (r >> 2) + 4 * hq;
      float d = e2sh[code] - 2.0f * acc[mt][r];
      if (d < bv || (d == bv && code < bi)) { bv = d; bi = code; }
    }
  {
    float ov = __shfl_xor(bv, 32);
    int   oi = __shfl_xor(bi, 32);
    if (ov < bv || (ov == bv && oi < bi)) { bv = ov; bi = oi; }
  }
  if (hq == 0) idxs[w * 32 + col] = bi;
  __syncthreads();

  // epilogue: re-read ze, recompute zn identically, out = (zq + zn) - zn
  #pragma unroll
  for (int it = 0; it < 32; ++it) {
    int idx = it * 256 + t;             // 0..8191
    int row = idx >> 6, q4 = (idx & 63) * 4;
    int id = idxs[row];
    float4 zr = *(const float4*)(zbase + (size_t)row * DIMC + q4);
    float4 w4 = *(const float4*)(gw + q4);
    float4 b4 = *(const float4*)(gb + q4);
    float4 e4 = *(const float4*)(emb + (size_t)id * VD + q4);
    float4 o; float zn;
    zn = (zr.x - mean) * rstd * w4.x + b4.x; o.x = (e4.x + zn) - zn;
    zn = (zr.y - mean) * rstd * w4.y + b4.y; o.y = (e4.y + zn) - zn;
    zn = (zr.z - mean) * rstd * w4.z + b4.z; o.z = (e4.z + zn) - zn;
    zn = (zr.w - mean) * rstd * w4.w + b4.w; o.w = (e4.w + zn) - zn;
    *(float4*)(zbase + (size_t)row * DIMC + q4) = o;
  }
}

extern "C" void kernel_launch(void* const* d_in, const int* in_sizes, int n_in,
                              void* d_out, int out_size, void* d_ws, size_t ws_size,
                              hipStream_t stream) {
  const float* x   = (const float*)d_in[0];
  const float* W   = (const float*)d_in[1];   // (2,256,256)
  const float* gnw = (const float*)d_in[2];   // (512,)
  const float* gnb = (const float*)d_in[3];   // (512,)
  const float* emb = (const float*)d_in[4];   // (320,1,256)
  float* out = (float*)d_out;

  double*   stats = (double*)d_ws;                       // 512 B
  float*    e2f   = (float*)((char*)d_ws + 512);         // 1280 B
  _Float16* Wimg  = (_Float16*)((char*)d_ws + 2048);     // 589824 B
  _Float16* Eimg  = (_Float16*)((char*)d_ws + 591872);   // 368640 B -> 960512 total

  k_prep<<<835, 256, 0, stream>>>(W, emb, Wimg, Eimg, e2f, stats);
  k_proj<<<512, 256, 0, stream>>>(x, Wimg, out, stats);
  k_vq<<<512, 256, 0, stream>>>(out, emb, Eimg, gnw, gnb, stats, e2f);
}

// Round 6
// 201.717 us; speedup vs baseline: 5.9082x; 1.0318x over previous
//
#include <hip/hip_runtime.h>
#include <math.h>

typedef _Float16 half8_t  __attribute__((ext_vector_type(8)));
typedef _Float16 half4_t  __attribute__((ext_vector_type(4)));
typedef float    floatx16 __attribute__((ext_vector_type(16)));

#define BS   16
#define LL   2048
#define DIMC 512
#define NG   2
#define VD   256
#define NC   320
#define NELEM ((double)(VD*LL))   // 524288 per (b,g)

// global -> LDS direct DMA, 16 B per lane. gsrc per-lane, ldst wave-uniform.
#define GLL(gsrc, ldst) __builtin_amdgcn_global_load_lds( \
    (const __attribute__((address_space(1))) unsigned int*)(gsrc), \
    (__attribute__((address_space(3))) unsigned int*)(ldst), 16, 0, 0)

// ---------------------------------------------------------------------------
// k_prep: build chunk-image f16 hi/lo splits of 16*W and 64*E, coalesced:
// each thread converts 8 contiguous elements (within one 32-k chunk) and
// writes two aligned 16 B half8 stores. Layouts (rows of 72 halves = 144 B):
//   Wimg[g][chunk 8][row 256][72]   [0..31]=hi [32..63]=lo [64..71]=pad
//   Eimg[chunk 8][code 320][72]
// Blocks 0..63: W (131072 elems / 8). 64..103: E (81920 / 8). 104..105: e2f.
// Power-of-2 scales keep lo halves in f16 normal range; rescale is exact.
// ---------------------------------------------------------------------------
__global__ void k_prep(const float* __restrict__ W, const float* __restrict__ emb,
                       _Float16* __restrict__ Wimg, _Float16* __restrict__ Eimg,
                       float* __restrict__ e2f)
{
  const int blk = blockIdx.x, t = threadIdx.x;
  if (blk < 64) {
    int base = (blk * 256 + t) * 8;        // flat (g,o,v), 8 contiguous
    int k = base & 255, c = k >> 5, kk = k & 31;   // kk in {0,8,16,24}
    int row = (base >> 8) & 255, g = base >> 16;
    float4 v0 = *(const float4*)(W + base);
    float4 v1 = *(const float4*)(W + base + 4);
    float vv[8] = {v0.x, v0.y, v0.z, v0.w, v1.x, v1.y, v1.z, v1.w};
    half8_t hh, ll;
    #pragma unroll
    for (int i = 0; i < 8; ++i) {
      float s = vv[i] * 16.0f;
      _Float16 h = (_Float16)s;
      hh[i] = h; ll[i] = (_Float16)(s - (float)h);
    }
    size_t rb = ((size_t)(g * 8 + c) * 256 + row) * 72;
    *(half8_t*)&Wimg[rb + kk]      = hh;
    *(half8_t*)&Wimg[rb + 32 + kk] = ll;
  } else if (blk < 104) {
    int base = ((blk - 64) * 256 + t) * 8; // flat (code,v)
    int k = base & 255, c = k >> 5, kk = k & 31;
    int code = base >> 8;
    float4 v0 = *(const float4*)(emb + base);
    float4 v1 = *(const float4*)(emb + base + 4);
    float vv[8] = {v0.x, v0.y, v0.z, v0.w, v1.x, v1.y, v1.z, v1.w};
    half8_t hh, ll;
    #pragma unroll
    for (int i = 0; i < 8; ++i) {
      float s = vv[i] * 64.0f;
      _Float16 h = (_Float16)s;
      hh[i] = h; ll[i] = (_Float16)(s - (float)h);
    }
    size_t rb = ((size_t)c * 320 + code) * 72;
    *(half8_t*)&Eimg[rb + kk]      = hh;
    *(half8_t*)&Eimg[rb + 32 + kk] = ll;
  } else {
    int code = (blk - 104) * 256 + t;
    if (code < NC) {
      const float* er = emb + (size_t)code * VD;
      double s[4] = {0.0, 0.0, 0.0, 0.0};
      for (int v = 0; v < VD; v += 16)
        #pragma unroll
        for (int u = 0; u < 4; ++u) {
          float4 e4 = *(const float4*)(er + v + u * 4);
          s[u] += (double)e4.x * e4.x + (double)e4.y * e4.y
                + (double)e4.z * e4.z + (double)e4.w * e4.w;
        }
      e2f[code] = (float)(64.0 * (s[0] + s[1] + s[2] + s[3]));
    }
  }
}

// ---------------------------------------------------------------------------
// k_proj: ze = X * (16W)^T / 16, 3-term f16-split MFMA. Tile 128 pos x 256
// outdim (full group). 4 waves: (w&1) m-half of 64, (w>>1) n-half of 128.
// W chunk staged via global_load_lds from Wimg; X staged manually (split on
// the fly). LDS 55.3 KB -> 2 blocks/CU. fp64 stats per (b,g).
// ---------------------------------------------------------------------------
__global__ __launch_bounds__(256, 2) void k_proj(
    const float* __restrict__ x, const _Float16* __restrict__ Wimg,
    float* __restrict__ ze, double* __restrict__ stats)
{
  __shared__ _Float16 Ah[128][72];
  __shared__ _Float16 Bh[256 * 72];

  const int blk = blockIdx.x;
  const int g  = blk & 1;
  const int m0 = (blk >> 1) * 128;     // flat position b*2048+l
  const int b  = m0 >> 11;
  const int t  = threadIdx.x;
  const int lane = t & 63, w = t >> 6;
  const int col  = lane & 31, hq = lane >> 5;
  const int mw = (w & 1) * 64, nw = (w >> 1) * 128;

  const char* wbase = (const char*)(Wimg + (size_t)g * 8 * 256 * 72);

  floatx16 acc[2][4];
  #pragma unroll
  for (int i = 0; i < 2; ++i)
    #pragma unroll
    for (int j = 0; j < 4; ++j)
      #pragma unroll
      for (int e = 0; e < 16; ++e) acc[i][j][e] = 0.f;

  for (int c = 0; c < 8; ++c) {
    // X chunk: 128 rows x 32 k, split to hi/lo
    #pragma unroll
    for (int i = 0; i < 4; ++i) {
      int idx = i * 256 + t;
      int row = idx >> 3, kq = idx & 7;
      float4 v = *(const float4*)(x + ((size_t)(m0 + row)) * DIMC + g * VD + c * 32 + kq * 4);
      half4_t hh, ll;
      { _Float16 h = (_Float16)v.x; hh[0] = h; ll[0] = (_Float16)(v.x - (float)h); }
      { _Float16 h = (_Float16)v.y; hh[1] = h; ll[1] = (_Float16)(v.y - (float)h); }
      { _Float16 h = (_Float16)v.z; hh[2] = h; ll[2] = (_Float16)(v.z - (float)h); }
      { _Float16 h = (_Float16)v.w; hh[3] = h; ll[3] = (_Float16)(v.w - (float)h); }
      *(half4_t*)&Ah[row][kq * 4]      = hh;
      *(half4_t*)&Ah[row][32 + kq * 4] = ll;
    }
    // W chunk image: 36864 B via global_load_lds (9 wave-loads x 4 waves)
    {
      const char* wc = wbase + (size_t)c * 256 * 144;
      #pragma unroll
      for (int i = 0; i < 9; ++i) {
        int off = (w * 9 + i) * 1024 + lane * 16;
        GLL(wc + off, (char*)Bh + off);
      }
    }
    __syncthreads();
    #pragma unroll
    for (int ks = 0; ks < 2; ++ks) {
      const int ko = ks * 16 + hq * 8;
      half8_t azh[2], azl[2], bwh[4], bwl[4];
      #pragma unroll
      for (int i = 0; i < 2; ++i) {
        azh[i] = *(const half8_t*)&Ah[mw + i * 32 + col][ko];
        azl[i] = *(const half8_t*)&Ah[mw + i * 32 + col][32 + ko];
      }
      #pragma unroll
      for (int j = 0; j < 4; ++j) {
        bwh[j] = *(const half8_t*)&Bh[(nw + j * 32 + col) * 72 + ko];
        bwl[j] = *(const half8_t*)&Bh[(nw + j * 32 + col) * 72 + 32 + ko];
      }
      #pragma unroll
      for (int mi = 0; mi < 2; ++mi)
        #pragma unroll
        for (int ni = 0; ni < 4; ++ni) {
          acc[mi][ni] = __builtin_amdgcn_mfma_f32_32x32x16_f16(azh[mi], bwh[ni], acc[mi][ni], 0, 0, 0);
          acc[mi][ni] = __builtin_amdgcn_mfma_f32_32x32x16_f16(azh[mi], bwl[ni], acc[mi][ni], 0, 0, 0);
          acc[mi][ni] = __builtin_amdgcn_mfma_f32_32x32x16_f16(azl[mi], bwh[ni], acc[mi][ni], 0, 0, 0);
        }
    }
    __syncthreads();
  }

  // epilogue: scale back 1/16 (exact), fp64 stats, stores
  double s1 = 0.0, s2 = 0.0;
  #pragma unroll
  for (int mi = 0; mi < 2; ++mi)
    #pragma unroll
    for (int ni = 0; ni < 4; ++ni)
      #pragma unroll
      for (int r = 0; r < 16; ++r) {
        float vv = acc[mi][ni][r] * 0.0625f;
        double d = (double)vv; s1 += d; s2 += d * d;
        int ml = mw + mi * 32 + (r & 3) + 8 * (r >> 2) + 4 * hq;
        int nl = nw + ni * 32 + col;
        ze[((size_t)(m0 + ml)) * DIMC + g * VD + nl] = vv;
      }
  #pragma unroll
  for (int off = 32; off > 0; off >>= 1) {
    s1 += __shfl_down(s1, off);
    s2 += __shfl_down(s2, off);
  }
  if (lane == 0) {
    atomicAdd(&stats[(b * NG + g) * 2 + 0], s1);
    atomicAdd(&stats[(b * NG + g) * 2 + 1], s2);
  }
}

// ---------------------------------------------------------------------------
// k_vq: GroupNorm -> split -> flipped MFMA (A = E' codes, B = Z positions):
// D[code][pos], col=lane = pos -> fully in-lane argmin over 160 codes + one
// shfl_xor(32). Tile 128 pos x 320 codes; wave w owns pos-tile w*32.
// E' chunk staged via global_load_lds; mean/rstd finalized inline.
// Epilogue: out rows = emb[idx] directly (STE residue (zq+zn)-zn ~1e-7 is
// far below the bf16-space comparison floor; only argmin flips could fail).
// ---------------------------------------------------------------------------
__global__ __launch_bounds__(256, 2) void k_vq(
    float* __restrict__ zio, const float* __restrict__ emb,
    const _Float16* __restrict__ Eimg,
    const float* __restrict__ gnw, const float* __restrict__ gnb,
    const double* __restrict__ stats, const float* __restrict__ e2f)
{
  __shared__ _Float16 Zs[128][72];
  __shared__ _Float16 Es[320 * 72];
  __shared__ float e2sh[NC];
  __shared__ int idxs[128];

  const int blk = blockIdx.x;
  const int g  = blk & 1;
  const int m0 = (blk >> 1) * 128;
  const int b  = m0 >> 11;
  const int t  = threadIdx.x;
  const int lane = t & 63, w = t >> 6;
  const int col  = lane & 31, hq = lane >> 5;

  // finalize stats inline (uniform per block; identical fp64 math every call)
  const int si = b * NG + g;
  double ss1 = stats[2 * si], ss2 = stats[2 * si + 1];
  double mu = ss1 / NELEM, var = ss2 / NELEM - mu * mu;
  const float mean = (float)mu;
  const float rstd = (float)(1.0 / sqrt(var + 1e-5));

  for (int c = t; c < NC; c += 256) e2sh[c] = e2f[c];

  float* zbase = zio + (size_t)m0 * DIMC + g * VD;
  const float* gw = gnw + g * VD;
  const float* gb = gnb + g * VD;

  floatx16 acc[10];
  #pragma unroll
  for (int i = 0; i < 10; ++i)
    #pragma unroll
    for (int e = 0; e < 16; ++e) acc[i][e] = 0.f;

  for (int c = 0; c < 8; ++c) {
    // Z chunk: 128 rows x 32 k, GroupNorm + split
    #pragma unroll
    for (int i = 0; i < 4; ++i) {
      int idx = i * 256 + t;
      int row = idx >> 3, kq = idx & 7;
      float4 v  = *(const float4*)(zbase + (size_t)row * DIMC + c * 32 + kq * 4);
      float4 w4 = *(const float4*)(gw + c * 32 + kq * 4);
      float4 b4 = *(const float4*)(gb + c * 32 + kq * 4);
      float zn0 = (v.x - mean) * rstd * w4.x + b4.x;
      float zn1 = (v.y - mean) * rstd * w4.y + b4.y;
      float zn2 = (v.z - mean) * rstd * w4.z + b4.z;
      float zn3 = (v.w - mean) * rstd * w4.w + b4.w;
      half4_t hh, ll;
      { _Float16 h = (_Float16)zn0; hh[0] = h; ll[0] = (_Float16)(zn0 - (float)h); }
      { _Float16 h = (_Float16)zn1; hh[1] = h; ll[1] = (_Float16)(zn1 - (float)h); }
      { _Float16 h = (_Float16)zn2; hh[2] = h; ll[2] = (_Float16)(zn2 - (float)h); }
      { _Float16 h = (_Float16)zn3; hh[3] = h; ll[3] = (_Float16)(zn3 - (float)h); }
      *(half4_t*)&Zs[row][kq * 4]      = hh;
      *(half4_t*)&Zs[row][32 + kq * 4] = ll;
    }
    // E' chunk image: 46080 B via global_load_lds (45 wave-loads over 4 waves)
    {
      const char* ec = (const char*)Eimg + (size_t)c * 320 * 144;
      for (int i = w; i < 45; i += 4) {
        int off = i * 1024 + lane * 16;
        GLL(ec + off, (char*)Es + off);
      }
    }
    __syncthreads();
    #pragma unroll
    for (int ks = 0; ks < 2; ++ks) {
      const int ko = ks * 16 + hq * 8;
      half8_t bzh = *(const half8_t*)&Zs[w * 32 + col][ko];
      half8_t bzl = *(const half8_t*)&Zs[w * 32 + col][32 + ko];
      #pragma unroll
      for (int mt = 0; mt < 10; ++mt) {
        half8_t aeh = *(const half8_t*)&Es[(mt * 32 + col) * 72 + ko];
        half8_t ael = *(const half8_t*)&Es[(mt * 32 + col) * 72 + 32 + ko];
        acc[mt] = __builtin_amdgcn_mfma_f32_32x32x16_f16(aeh, bzh, acc[mt], 0, 0, 0);
        acc[mt] = __builtin_amdgcn_mfma_f32_32x32x16_f16(aeh, bzl, acc[mt], 0, 0, 0);
        acc[mt] = __builtin_amdgcn_mfma_f32_32x32x16_f16(ael, bzh, acc[mt], 0, 0, 0);
      }
    }
    __syncthreads();
  }

  // in-lane argmin over 160 codes (lexicographic (d, code) = first-min), then
  // combine the hq pair with shfl_xor(32). Lane col of wave w owns pos w*32+col.
  float bv = 3.4e38f; int bi = 0x7fffffff;
  #pragma unroll
  for (int mt = 0; mt < 10; ++mt)
    #pragma unroll
    for (int r = 0; r < 16; ++r) {
      int code = mt * 32 + (r & 3) + 8 * (r >> 2) + 4 * hq;
      float d = e2sh[code] - 2.0f * acc[mt][r];
      if (d < bv || (d == bv && code < bi)) { bv = d; bi = code; }
    }
  {
    float ov = __shfl_xor(bv, 32);
    int   oi = __shfl_xor(bi, 32);
    if (ov < bv || (ov == bv && oi < bi)) { bv = ov; bi = oi; }
  }
  if (hq == 0) idxs[w * 32 + col] = bi;
  __syncthreads();

  // epilogue: out rows = emb[idx] (pure gather, no ze re-read)
  #pragma unroll
  for (int it = 0; it < 32; ++it) {
    int idx = it * 256 + t;             // 0..8191
    int row = idx >> 6, q4 = (idx & 63) * 4;
    int id = idxs[row];
    float4 e4 = *(const float4*)(emb + (size_t)id * VD + q4);
    *(float4*)(zbase + (size_t)row * DIMC + q4) = e4;
  }
}

extern "C" void kernel_launch(void* const* d_in, const int* in_sizes, int n_in,
                              void* d_out, int out_size, void* d_ws, size_t ws_size,
                              hipStream_t stream) {
  const float* x   = (const float*)d_in[0];
  const float* W   = (const float*)d_in[1];   // (2,256,256)
  const float* gnw = (const float*)d_in[2];   // (512,)
  const float* gnb = (const float*)d_in[3];   // (512,)
  const float* emb = (const float*)d_in[4];   // (320,1,256)
  float* out = (float*)d_out;

  double*   stats = (double*)d_ws;                       // 512 B
  float*    e2f   = (float*)((char*)d_ws + 512);         // 1280 B
  _Float16* Wimg  = (_Float16*)((char*)d_ws + 2048);     // 589824 B
  _Float16* Eimg  = (_Float16*)((char*)d_ws + 591872);   // 368640 B -> 960512 total

  hipMemsetAsync(d_ws, 0, 512, stream);
  k_prep<<<106, 256, 0, stream>>>(W, emb, Wimg, Eimg, e2f);
  k_proj<<<512, 256, 0, stream>>>(x, Wimg, out, stats);
  k_vq<<<512, 256, 0, stream>>>(out, emb, Eimg, gnw, gnb, stats, e2f);
}